// Round 4
// baseline (408.571 us; speedup 1.0000x reference)
//
#include <hip/hip_runtime.h>
#include <stdint.h>

#define S_LEN 2048
#define NB 32
#define NE 512
#define NU 512
#define NP 256

typedef __bf16 bf16;
typedef __bf16 bf16x8 __attribute__((ext_vector_type(8)));
typedef __bf16 bf16x4 __attribute__((ext_vector_type(4)));
typedef float f32x4 __attribute__((ext_vector_type(4)));
typedef float f32x8 __attribute__((ext_vector_type(8)));

__device__ __forceinline__ void gload16(const void* g, void* l) {
    __builtin_amdgcn_global_load_lds(
        (__attribute__((address_space(1))) void*)g,
        (__attribute__((address_space(3))) void*)l, 16, 0, 0);
}

// Stage a 128-row x 32-col bf16 tile (row stride SR elems) into an 8KB LDS
// buffer, 2 chunks per thread. LDS chunk c holds row c>>2, k-quad
// q = (c&3) ^ ((c>>3)&3)  (self-inverse permutation; the matching ds_read
// applies the same XOR -> roundtrip identity, 2-way bank spread = free).
__device__ __forceinline__ void stage_tile(const bf16* __restrict__ src, int SR,
                                           bf16* lds, int tid) {
#pragma unroll
    for (int rnd = 0; rnd < 2; ++rnd) {
        const int c = rnd * 256 + tid;
        const int row = c >> 2;
        const int q = (c & 3) ^ ((c >> 3) & 3);
        gload16(src + (size_t)row * SR + q * 8, lds + c * 8);
    }
}

// ---------------- kernel 0b: w1 fp32 -> bf16 hi/lo --------------------------
__global__ __launch_bounds__(256) void k_wconv(
    const float* __restrict__ w1, bf16* __restrict__ wHi, bf16* __restrict__ wLo)
{
    const int i = (blockIdx.x * 256 + threadIdx.x) * 4;
    const float4 v = *(const float4*)(w1 + i);
    const float vv[4] = {v.x, v.y, v.z, v.w};
    bf16x4 oh, ol;
#pragma unroll
    for (int q = 0; q < 4; ++q) {
        const bf16 hb = (bf16)vv[q];
        oh[q] = hb;
        ol[q] = (bf16)(vv[q] - (float)hb);
    }
    *(bf16x4*)(wHi + i) = oh;
    *(bf16x4*)(wLo + i) = ol;
}

// ---------------- kernel 1: GEMM1 + silu + logits + softmax -----------------
__global__ __launch_bounds__(256, 2) void k_gemm1(
    const float* __restrict__ seq,
    const bf16* __restrict__ w1H, const bf16* __restrict__ w1L,
    const float* __restrict__ b1v, const float* __restrict__ w2,
    const float* __restrict__ b2v, float* __restrict__ actions)
{
    __shared__ __align__(16) bf16 BhL[2][4096];
    __shared__ __align__(16) bf16 BlL[2][4096];
    const int tid = threadIdx.x;
    const int wid = tid >> 6;
    const int lane = tid & 63;
    const int lr = lane & 15, lg = lane >> 4;
    const int m0 = blockIdx.x << 7;

    const float* arow0 = seq + (size_t)(m0 + wid * 32 + lr) * NE + lg * 8;
    const float* arow1 = arow0 + 16 * NE;
    const int lroff = lr * 64 + (lg ^ ((lr >> 1) & 3)) * 16;

    float plog[3][2][4];
#pragma unroll
    for (int a = 0; a < 3; ++a)
#pragma unroll
        for (int i = 0; i < 2; ++i)
#pragma unroll
            for (int q = 0; q < 4; ++q) plog[a][i][q] = 0.f;

    f32x4 acc[2][8];
    stage_tile(w1H, NE, BhL[0], tid);
    stage_tile(w1L, NE, BlL[0], tid);
    f32x8 Aa0 = *(const f32x8*)(arow0);
    f32x8 Aa1 = *(const f32x8*)(arow1);
    f32x8 Ab0, Ab1;

#define G1_BODY(g, buf, Ac0, Ac1, An0, An1) do {                              \
        __syncthreads();                                                      \
        if (((g) & 15) == 0) {                                                \
            _Pragma("unroll") for (int i = 0; i < 2; ++i)                     \
            _Pragma("unroll") for (int j = 0; j < 8; ++j)                     \
                acc[i][j] = (f32x4)(0.f);                                     \
        }                                                                     \
        bf16x8 bh[8], bl[8];                                                  \
        _Pragma("unroll") for (int j = 0; j < 8; ++j) {                       \
            bh[j] = *(const bf16x8*)((const char*)BhL[buf] + j * 1024 + lroff);\
            bl[j] = *(const bf16x8*)((const char*)BlL[buf] + j * 1024 + lroff);\
        }                                                                     \
        __syncthreads();                                                      \
        if ((g) < 63) {                                                       \
            const int gn = (g) + 1;                                           \
            const int u0n = (gn >> 4) << 7;                                   \
            const int k0n = (gn & 15) << 5;                                   \
            stage_tile(w1H + (size_t)u0n * NE + k0n, NE, BhL[(buf) ^ 1], tid);\
            stage_tile(w1L + (size_t)u0n * NE + k0n, NE, BlL[(buf) ^ 1], tid);\
            An0 = *(const f32x8*)(arow0 + k0n);                               \
            An1 = *(const f32x8*)(arow1 + k0n);                               \
        }                                                                     \
        bf16x8 Ah0, Al0, Ah1, Al1;                                            \
        _Pragma("unroll") for (int q = 0; q < 8; ++q) {                       \
            const bf16 h0 = (bf16)Ac0[q];                                     \
            Ah0[q] = h0; Al0[q] = (bf16)(Ac0[q] - (float)h0);                 \
            const bf16 h1 = (bf16)Ac1[q];                                     \
            Ah1[q] = h1; Al1[q] = (bf16)(Ac1[q] - (float)h1);                 \
        }                                                                     \
        _Pragma("unroll") for (int j = 0; j < 8; ++j) {                       \
            acc[0][j] = __builtin_amdgcn_mfma_f32_16x16x32_bf16(Ah0, bh[j], acc[0][j], 0, 0, 0); \
            acc[0][j] = __builtin_amdgcn_mfma_f32_16x16x32_bf16(Ah0, bl[j], acc[0][j], 0, 0, 0); \
            acc[0][j] = __builtin_amdgcn_mfma_f32_16x16x32_bf16(Al0, bh[j], acc[0][j], 0, 0, 0); \
            acc[1][j] = __builtin_amdgcn_mfma_f32_16x16x32_bf16(Ah1, bh[j], acc[1][j], 0, 0, 0); \
            acc[1][j] = __builtin_amdgcn_mfma_f32_16x16x32_bf16(Ah1, bl[j], acc[1][j], 0, 0, 0); \
            acc[1][j] = __builtin_amdgcn_mfma_f32_16x16x32_bf16(Al1, bh[j], acc[1][j], 0, 0, 0); \
        }                                                                     \
        if (((g) & 15) == 15) {                                               \
            const int u0 = ((g) >> 4) << 7;                                   \
            _Pragma("unroll") for (int j = 0; j < 8; ++j) {                   \
                const int col = u0 + j * 16 + lr;                             \
                const float b1c = b1v[col];                                   \
                const float w20 = w2[col], w21 = w2[NU + col], w22 = w2[2 * NU + col]; \
                _Pragma("unroll") for (int i = 0; i < 2; ++i)                 \
                _Pragma("unroll") for (int q = 0; q < 4; ++q) {               \
                    const float x = acc[i][j][q] + b1c;                       \
                    const float hgate = x / (1.f + __expf(-x));               \
                    plog[0][i][q] = fmaf(hgate, w20, plog[0][i][q]);          \
                    plog[1][i][q] = fmaf(hgate, w21, plog[1][i][q]);          \
                    plog[2][i][q] = fmaf(hgate, w22, plog[2][i][q]);          \
                }                                                             \
            }                                                                 \
        }                                                                     \
    } while (0)

    for (int gg = 0; gg < 32; ++gg) {
        G1_BODY(2 * gg, 0, Aa0, Aa1, Ab0, Ab1);
        G1_BODY(2 * gg + 1, 1, Ab0, Ab1, Aa0, Aa1);
    }
#undef G1_BODY

#pragma unroll
    for (int m = 1; m < 16; m <<= 1) {
#pragma unroll
        for (int a = 0; a < 3; ++a)
#pragma unroll
            for (int i = 0; i < 2; ++i)
#pragma unroll
                for (int q = 0; q < 4; ++q)
                    plog[a][i][q] += __shfl_xor(plog[a][i][q], m);
    }
    const float bb0 = b2v[0], bb1 = b2v[1], bb2 = b2v[2];
    if (lr == 0) {
#pragma unroll
        for (int i = 0; i < 2; ++i)
#pragma unroll
            for (int q = 0; q < 4; ++q) {
                const int row = m0 + wid * 32 + i * 16 + lg * 4 + q;
                const float l0 = plog[0][i][q] + bb0;
                const float l1 = plog[1][i][q] + bb1;
                const float l2 = plog[2][i][q] + bb2;
                const float mx = fmaxf(l0, fmaxf(l1, l2));
                const float e0 = __expf(l0 - mx), e1 = __expf(l1 - mx), e2 = __expf(l2 - mx);
                const float inv = 1.f / (e0 + e1 + e2);
                *(float4*)(actions + (size_t)row * 4) = make_float4(e0 * inv, e1 * inv, e2 * inv, 0.f);
            }
    }
}

// ---------------- fused kernel: scan (blocks 0..31) + prep transpose --------
// scan: one wave per batch, act staged through LDS 256 steps ahead
//       (global_load_lds double-buffer) to kill the per-step L2-latency stall.
// prep: seq[b][s][e] fp32 -> seqtH[b][e][s] bf16 (as before, bid-32).
union SPMem {
    float tile[64][65];
    float4 actbuf[2][256];
};

__global__ __launch_bounds__(256) void k_scan_prep(
    const float* __restrict__ actions, bf16* __restrict__ wsT,
    const float* __restrict__ seq, bf16* __restrict__ tHi)
{
    __shared__ SPMem sm;
    if (blockIdx.x < 32) {
        if (threadIdx.x >= 64) return;
        const int b = blockIdx.x;
        const int lane = threadIdx.x;
        const int h = lane & 15;
        const int wq = lane >> 4;
        float T0 = 0.f, T1 = 0.f, T2 = 0.f, T3 = 0.f;
        if (lane == 48) T3 = 1.f;          // (h=0, w=15)
        float rs = (h == 0) ? 1.f : 0.f;
        const float4* actb = (const float4*)actions + (size_t)b * S_LEN;
        bf16* ob = wsT + ((size_t)b * NP + h * 16 + wq * 4) * S_LEN;

        // stage chunk 0 (act rows [1792, 2048))
#pragma unroll
        for (int j = 0; j < 4; ++j)
            gload16(actb + 1792 + j * 64 + lane, &sm.actbuf[0][j * 64]);

        float nT0 = __shfl_down(T0, 16);

        for (int c = 0; c < 8; ++c) {
            asm volatile("s_waitcnt vmcnt(0)" ::: "memory");
            if (c < 7) {
                const int rs0 = 1792 - (c + 1) * 256;
#pragma unroll
                for (int j = 0; j < 4; ++j)
                    gload16(actb + rs0 + j * 64 + lane, &sm.actbuf[(c + 1) & 1][j * 64]);
            }
            const float4* lb = sm.actbuf[c & 1];
            for (int w = 0; w < 32; ++w) {
                const int tbase = 2040 - c * 256 - w * 8;   // t in [tbase, tbase+8)
                // prefetch the window's 8 act rows (descending t) from LDS
                float4 av0 = lb[(tbase + 7) & 255];
                float4 av1 = lb[(tbase + 6) & 255];
                float4 av2 = lb[(tbase + 5) & 255];
                float4 av3 = lb[(tbase + 4) & 255];
                float4 av4 = lb[(tbase + 3) & 255];
                float4 av5 = lb[(tbase + 2) & 255];
                float4 av6 = lb[(tbase + 1) & 255];
                float4 av7 = lb[(tbase + 0) & 255];
                bf16x8 fr0, fr1, fr2, fr3;
#define SCAN_STEP(Av, fi) do {                                                \
        const float a0 = (Av).x, a1 = (Av).y, a2 = (Av).z;                    \
        const float s01 = a0 + a1;                                            \
        const float s02 = a0 + a2;                                            \
        fr0[fi] = (bf16)(s01 * T0);                                           \
        fr1[fi] = (bf16)(s01 * T1);                                           \
        fr2[fi] = (bf16)(s01 * T2);                                           \
        fr3[fi] = (bf16)(s01 * T3);                                           \
        const int rsi = __builtin_amdgcn_update_dpp(                          \
            0, __builtin_bit_cast(int, rs), 0x111, 0xF, 0xF, true);           \
        const float rsp = __builtin_bit_cast(float, rsi);                     \
        const float sums = a1 * rsp;                                          \
        const float q1 = a0 * T1, q2 = a0 * T2, q3 = a0 * T3;                 \
        const float qe = (wq == 3) ? sums : a0 * nT0;                         \
        T0 = fmaf(a2, T0, q1);                                                \
        T1 = fmaf(a2, T1, q2);                                                \
        T2 = fmaf(a2, T2, q3);                                                \
        T3 = fmaf(a2, T3, qe);                                                \
        rs = fmaf(s02, rs, sums);                                             \
        nT0 = __shfl_down(T0, 16);                                            \
    } while (0)
                SCAN_STEP(av0, 7);
                SCAN_STEP(av1, 6);
                SCAN_STEP(av2, 5);
                SCAN_STEP(av3, 4);
                SCAN_STEP(av4, 3);
                SCAN_STEP(av5, 2);
                SCAN_STEP(av6, 1);
                SCAN_STEP(av7, 0);
#undef SCAN_STEP
                *(bf16x8*)(ob + (size_t)0 * S_LEN + tbase) = fr0;
                *(bf16x8*)(ob + (size_t)1 * S_LEN + tbase) = fr1;
                *(bf16x8*)(ob + (size_t)2 * S_LEN + tbase) = fr2;
                *(bf16x8*)(ob + (size_t)3 * S_LEN + tbase) = fr3;
            }
        }
        return;
    }
    // ---- prep transpose path ----
    const int bid = blockIdx.x - 32;
    const int b = bid >> 8;
    const int r = bid & 255;
    const int s0 = (r & 31) << 6;
    const int e0 = (r >> 5) << 6;
    const int t = threadIdx.x;
    const int tx = t & 15, ty = t >> 4;
    const float* src = seq + ((size_t)b * S_LEN + s0) * NE + e0;
#pragma unroll
    for (int i = 0; i < 4; ++i) {
        const int row = ty + i * 16;
        const float4 v = *(const float4*)(src + (size_t)row * NE + tx * 4);
        sm.tile[row][tx * 4 + 0] = v.x; sm.tile[row][tx * 4 + 1] = v.y;
        sm.tile[row][tx * 4 + 2] = v.z; sm.tile[row][tx * 4 + 3] = v.w;
    }
    __syncthreads();
    const int sx = t & 7, ey = t >> 3;
#pragma unroll
    for (int jj = 0; jj < 2; ++jj) {
        const int er = ey + jj * 32;
        bf16x8 oh;
#pragma unroll
        for (int q = 0; q < 8; ++q) oh[q] = (bf16)sm.tile[sx * 8 + q][er];
        *(bf16x8*)(tHi + ((size_t)b * NE + e0 + er) * S_LEN + s0 + sx * 8) = oh;
    }
}

// ---------------- kernel 3: GEMM2 partials (2-way k-split, LDS-staged) ------
__global__ __launch_bounds__(256, 2) void k_gemm2(
    const bf16* __restrict__ wsT, const bf16* __restrict__ seqtH,
    float* __restrict__ part)
{
    __shared__ __align__(16) bf16 AL[2][4096];
    __shared__ __align__(16) bf16 BL[2][4096];
    const int tid = threadIdx.x;
    const int wid = tid >> 6;
    const int lane = tid & 63;
    const int lr = lane & 15, lg = lane >> 4;
    const int bid = blockIdx.x;
    const int b = bid >> 4;
    const int sub = bid & 15;
    const int kc = sub >> 3;
    const int p0 = ((sub >> 2) & 1) << 7;
    const int e0 = (sub & 3) << 7;

    const bf16* Abase = wsT + ((size_t)b * NP + p0) * S_LEN + kc * 1024;
    const bf16* Bbase = seqtH + ((size_t)b * NE + e0) * S_LEN + kc * 1024;
    const int lroff = lr * 64 + (lg ^ ((lr >> 1) & 3)) * 16;

    f32x4 acc[2][8];
#pragma unroll
    for (int i = 0; i < 2; ++i)
#pragma unroll
        for (int j = 0; j < 8; ++j) acc[i][j] = (f32x4)(0.f);

    stage_tile(Abase, S_LEN, AL[0], tid);
    stage_tile(Bbase, S_LEN, BL[0], tid);

#define G2_BODY(kt, buf) do {                                                 \
        __syncthreads();                                                      \
        bf16x8 af[2], bfv[8];                                                 \
        _Pragma("unroll") for (int i = 0; i < 2; ++i)                         \
            af[i] = *(const bf16x8*)((const char*)AL[buf]                     \
                     + (wid * 32 + i * 16) * 64 + lroff);                     \
        _Pragma("unroll") for (int j = 0; j < 8; ++j)                         \
            bfv[j] = *(const bf16x8*)((const char*)BL[buf] + j * 1024 + lroff);\
        __syncthreads();                                                      \
        if ((kt) < 31) {                                                      \
            stage_tile(Abase + ((kt) + 1) * 32, S_LEN, AL[(buf) ^ 1], tid);   \
            stage_tile(Bbase + ((kt) + 1) * 32, S_LEN, BL[(buf) ^ 1], tid);   \
        }                                                                     \
        _Pragma("unroll") for (int j = 0; j < 8; ++j) {                       \
            acc[0][j] = __builtin_amdgcn_mfma_f32_16x16x32_bf16(af[0], bfv[j], acc[0][j], 0, 0, 0); \
            acc[1][j] = __builtin_amdgcn_mfma_f32_16x16x32_bf16(af[1], bfv[j], acc[1][j], 0, 0, 0); \
        }                                                                     \
    } while (0)

    for (int kk = 0; kk < 16; ++kk) {
        G2_BODY(2 * kk, 0);
        G2_BODY(2 * kk + 1, 1);
    }
#undef G2_BODY

    float* obp = part + (((size_t)kc * NB + b) * NP + p0 + wid * 32) * NE + e0;
#pragma unroll
    for (int i = 0; i < 2; ++i)
#pragma unroll
        for (int j = 0; j < 8; ++j)
#pragma unroll
            for (int q = 0; q < 4; ++q)
                obp[(size_t)(i * 16 + lg * 4 + q) * NE + j * 16 + lr] = acc[i][j][q];
}

// ---------------- kernel 4: reduce the 2 partials ---------------------------
__global__ __launch_bounds__(256) void k_gred(
    const float* __restrict__ part, float* __restrict__ outp)
{
    const size_t i = ((size_t)blockIdx.x * 256 + threadIdx.x) * 4;
    const float4 p0 = *(const float4*)(part + i);
    const float4 p1 = *(const float4*)(part + ((size_t)NB * NP * NE) + i);
    *(float4*)(outp + i) = make_float4(p0.x + p1.x, p0.y + p1.y,
                                       p0.z + p1.z, p0.w + p1.w);
}

// ---------------- launch ----------------------------------------------------
extern "C" void kernel_launch(void* const* d_in, const int* in_sizes, int n_in,
                              void* d_out, int out_size, void* d_ws, size_t ws_size,
                              hipStream_t stream) {
    (void)in_sizes; (void)n_in; (void)out_size; (void)ws_size;
    const float* seq = (const float*)d_in[0];
    const float* w1  = (const float*)d_in[1];
    const float* b1  = (const float*)d_in[2];
    const float* w2  = (const float*)d_in[3];
    const float* b2  = (const float*)d_in[4];
    float* outp = (float*)d_out;

    char* ws = (char*)d_ws;
    bf16*  seqtH   = (bf16*)(ws);                        // 64 MB [b][e][s]
    bf16*  wsT     = (bf16*)(ws + (64ull << 20));        // 32 MB [b][p][t]
    float* actions = (float*)(ws + (96ull << 20));       // 1 MB  [b*S][4]
    bf16*  w1H     = (bf16*)(ws + (97ull << 20));        // 512 KB
    bf16*  w1L     = (bf16*)(ws + (97ull << 20) + (512u << 10)); // 512 KB
    float* part    = (float*)(ws + (98ull << 20));       // 32 MB [2][b][p][e]

    hipLaunchKernelGGL(k_wconv, dim3(256),  dim3(256), 0, stream, w1, w1H, w1L);
    hipLaunchKernelGGL(k_gemm1, dim3(512),  dim3(256), 0, stream,
                       seq, w1H, w1L, b1, w2, b2, actions);
    hipLaunchKernelGGL(k_scan_prep, dim3(32 + 8192), dim3(256), 0, stream,
                       actions, wsT, seq, seqtH);
    hipLaunchKernelGGL(k_gemm2, dim3(512),  dim3(256), 0, stream, wsT, seqtH, part);
    hipLaunchKernelGGL(k_gred,  dim3(4096), dim3(256), 0, stream, part, outp);
}

// Round 5
// 380.720 us; speedup vs baseline: 1.0732x; 1.0732x over previous
//
#include <hip/hip_runtime.h>
#include <stdint.h>

#define S_LEN 2048
#define NB 32
#define NE 512
#define NU 512
#define NP 256

typedef __bf16 bf16;
typedef __bf16 bf16x8 __attribute__((ext_vector_type(8)));
typedef __bf16 bf16x4 __attribute__((ext_vector_type(4)));
typedef float f32x4 __attribute__((ext_vector_type(4)));
typedef float f32x8 __attribute__((ext_vector_type(8)));

__device__ __forceinline__ void gload16(const void* g, void* l) {
    __builtin_amdgcn_global_load_lds(
        (__attribute__((address_space(1))) void*)g,
        (__attribute__((address_space(3))) void*)l, 16, 0, 0);
}

// DPP helpers: VALU-pipe lane shifts within 16-lane rows, bound_ctrl -> 0.
__device__ __forceinline__ float dpp_shr1_z(float x) {   // lane i <- i-1
    return __builtin_bit_cast(float, __builtin_amdgcn_update_dpp(
        0, __builtin_bit_cast(int, x), 0x111, 0xF, 0xF, true));
}
__device__ __forceinline__ float dpp_shl1_z(float x) {   // lane i <- i+1
    return __builtin_bit_cast(float, __builtin_amdgcn_update_dpp(
        0, __builtin_bit_cast(int, x), 0x101, 0xF, 0xF, true));
}

// Stage a 128-row x 32-col bf16 tile (row stride SR elems) into an 8KB LDS
// buffer, 2 chunks per thread; self-inverse k-quad permutation.
__device__ __forceinline__ void stage_tile(const bf16* __restrict__ src, int SR,
                                           bf16* lds, int tid) {
#pragma unroll
    for (int rnd = 0; rnd < 2; ++rnd) {
        const int c = rnd * 256 + tid;
        const int row = c >> 2;
        const int q = (c & 3) ^ ((c >> 3) & 3);
        gload16(src + (size_t)row * SR + q * 8, lds + c * 8);
    }
}

// ---------------- kernel 0b: w1 fp32 -> bf16 hi/lo --------------------------
__global__ __launch_bounds__(256) void k_wconv(
    const float* __restrict__ w1, bf16* __restrict__ wHi, bf16* __restrict__ wLo)
{
    const int i = (blockIdx.x * 256 + threadIdx.x) * 4;
    const float4 v = *(const float4*)(w1 + i);
    const float vv[4] = {v.x, v.y, v.z, v.w};
    bf16x4 oh, ol;
#pragma unroll
    for (int q = 0; q < 4; ++q) {
        const bf16 hb = (bf16)vv[q];
        oh[q] = hb;
        ol[q] = (bf16)(vv[q] - (float)hb);
    }
    *(bf16x4*)(wHi + i) = oh;
    *(bf16x4*)(wLo + i) = ol;
}

// ---------------- kernel 1: GEMM1 + silu + logits + softmax -----------------
__global__ __launch_bounds__(256, 2) void k_gemm1(
    const float* __restrict__ seq,
    const bf16* __restrict__ w1H, const bf16* __restrict__ w1L,
    const float* __restrict__ b1v, const float* __restrict__ w2,
    const float* __restrict__ b2v, float* __restrict__ actions)
{
    __shared__ __align__(16) bf16 BhL[2][4096];
    __shared__ __align__(16) bf16 BlL[2][4096];
    const int tid = threadIdx.x;
    const int wid = tid >> 6;
    const int lane = tid & 63;
    const int lr = lane & 15, lg = lane >> 4;
    const int m0 = blockIdx.x << 7;

    const float* arow0 = seq + (size_t)(m0 + wid * 32 + lr) * NE + lg * 8;
    const float* arow1 = arow0 + 16 * NE;
    const int lroff = lr * 64 + (lg ^ ((lr >> 1) & 3)) * 16;

    float plog[3][2][4];
#pragma unroll
    for (int a = 0; a < 3; ++a)
#pragma unroll
        for (int i = 0; i < 2; ++i)
#pragma unroll
            for (int q = 0; q < 4; ++q) plog[a][i][q] = 0.f;

    f32x4 acc[2][8];
    stage_tile(w1H, NE, BhL[0], tid);
    stage_tile(w1L, NE, BlL[0], tid);
    f32x8 Aa0 = *(const f32x8*)(arow0);
    f32x8 Aa1 = *(const f32x8*)(arow1);
    f32x8 Ab0, Ab1;

#define G1_BODY(g, buf, Ac0, Ac1, An0, An1) do {                              \
        __syncthreads();                                                      \
        if (((g) & 15) == 0) {                                                \
            _Pragma("unroll") for (int i = 0; i < 2; ++i)                     \
            _Pragma("unroll") for (int j = 0; j < 8; ++j)                     \
                acc[i][j] = (f32x4)(0.f);                                     \
        }                                                                     \
        bf16x8 bh[8], bl[8];                                                  \
        _Pragma("unroll") for (int j = 0; j < 8; ++j) {                       \
            bh[j] = *(const bf16x8*)((const char*)BhL[buf] + j * 1024 + lroff);\
            bl[j] = *(const bf16x8*)((const char*)BlL[buf] + j * 1024 + lroff);\
        }                                                                     \
        __syncthreads();                                                      \
        if ((g) < 63) {                                                       \
            const int gn = (g) + 1;                                           \
            const int u0n = (gn >> 4) << 7;                                   \
            const int k0n = (gn & 15) << 5;                                   \
            stage_tile(w1H + (size_t)u0n * NE + k0n, NE, BhL[(buf) ^ 1], tid);\
            stage_tile(w1L + (size_t)u0n * NE + k0n, NE, BlL[(buf) ^ 1], tid);\
            An0 = *(const f32x8*)(arow0 + k0n);                               \
            An1 = *(const f32x8*)(arow1 + k0n);                               \
        }                                                                     \
        bf16x8 Ah0, Al0, Ah1, Al1;                                            \
        _Pragma("unroll") for (int q = 0; q < 8; ++q) {                       \
            const bf16 h0 = (bf16)Ac0[q];                                     \
            Ah0[q] = h0; Al0[q] = (bf16)(Ac0[q] - (float)h0);                 \
            const bf16 h1 = (bf16)Ac1[q];                                     \
            Ah1[q] = h1; Al1[q] = (bf16)(Ac1[q] - (float)h1);                 \
        }                                                                     \
        _Pragma("unroll") for (int j = 0; j < 8; ++j) {                       \
            acc[0][j] = __builtin_amdgcn_mfma_f32_16x16x32_bf16(Ah0, bh[j], acc[0][j], 0, 0, 0); \
            acc[0][j] = __builtin_amdgcn_mfma_f32_16x16x32_bf16(Ah0, bl[j], acc[0][j], 0, 0, 0); \
            acc[0][j] = __builtin_amdgcn_mfma_f32_16x16x32_bf16(Al0, bh[j], acc[0][j], 0, 0, 0); \
            acc[1][j] = __builtin_amdgcn_mfma_f32_16x16x32_bf16(Ah1, bh[j], acc[1][j], 0, 0, 0); \
            acc[1][j] = __builtin_amdgcn_mfma_f32_16x16x32_bf16(Ah1, bl[j], acc[1][j], 0, 0, 0); \
            acc[1][j] = __builtin_amdgcn_mfma_f32_16x16x32_bf16(Al1, bh[j], acc[1][j], 0, 0, 0); \
        }                                                                     \
        if (((g) & 15) == 15) {                                               \
            const int u0 = ((g) >> 4) << 7;                                   \
            _Pragma("unroll") for (int j = 0; j < 8; ++j) {                   \
                const int col = u0 + j * 16 + lr;                             \
                const float b1c = b1v[col];                                   \
                const float w20 = w2[col], w21 = w2[NU + col], w22 = w2[2 * NU + col]; \
                _Pragma("unroll") for (int i = 0; i < 2; ++i)                 \
                _Pragma("unroll") for (int q = 0; q < 4; ++q) {               \
                    const float x = acc[i][j][q] + b1c;                       \
                    const float hgate = x / (1.f + __expf(-x));               \
                    plog[0][i][q] = fmaf(hgate, w20, plog[0][i][q]);          \
                    plog[1][i][q] = fmaf(hgate, w21, plog[1][i][q]);          \
                    plog[2][i][q] = fmaf(hgate, w22, plog[2][i][q]);          \
                }                                                             \
            }                                                                 \
        }                                                                     \
    } while (0)

    for (int gg = 0; gg < 32; ++gg) {
        G1_BODY(2 * gg, 0, Aa0, Aa1, Ab0, Ab1);
        G1_BODY(2 * gg + 1, 1, Ab0, Ab1, Aa0, Aa1);
    }
#undef G1_BODY

#pragma unroll
    for (int m = 1; m < 16; m <<= 1) {
#pragma unroll
        for (int a = 0; a < 3; ++a)
#pragma unroll
            for (int i = 0; i < 2; ++i)
#pragma unroll
                for (int q = 0; q < 4; ++q)
                    plog[a][i][q] += __shfl_xor(plog[a][i][q], m);
    }
    const float bb0 = b2v[0], bb1 = b2v[1], bb2 = b2v[2];
    if (lr == 0) {
#pragma unroll
        for (int i = 0; i < 2; ++i)
#pragma unroll
            for (int q = 0; q < 4; ++q) {
                const int row = m0 + wid * 32 + i * 16 + lg * 4 + q;
                const float l0 = plog[0][i][q] + bb0;
                const float l1 = plog[1][i][q] + bb1;
                const float l2 = plog[2][i][q] + bb2;
                const float mx = fmaxf(l0, fmaxf(l1, l2));
                const float e0 = __expf(l0 - mx), e1 = __expf(l1 - mx), e2 = __expf(l2 - mx);
                const float inv = 1.f / (e0 + e1 + e2);
                *(float4*)(actions + (size_t)row * 4) = make_float4(e0 * inv, e1 * inv, e2 * inv, 0.f);
            }
    }
}

// ---------------- fused kernel: scan (blocks 0..31) + prep transpose --------
// scan per chunk of 256 steps: (1) rs-subloop (lanes 0..15, h=lane, DPP
// row_shr:1) writes sums[t][h] to LDS; (2) T-subloop with lane = h*4+wq so
// the T[w+1] neighbor is lane+1 = DPP row_shl:1 (VALU). NO ds_bpermute in
// either recurrence. act staged via global_load_lds double-buffer.
union SPMem {
    float tile[64][65];                 // prep path
    struct {
        float4 actbuf[2][256];          // 8 KB
        float  sums[256][16];           // 16 KB
    } s;
};

__global__ __launch_bounds__(256) void k_scan_prep(
    const float* __restrict__ actions, bf16* __restrict__ wsT,
    const float* __restrict__ seq, bf16* __restrict__ tHi)
{
    __shared__ SPMem sm;
    if (blockIdx.x < 32) {
        if (threadIdx.x >= 64) return;
        const int b = blockIdx.x;
        const int lane = threadIdx.x;
        const int h4 = lane >> 2;          // h owned in T-phase
        const int wq = lane & 3;           // w-quad in T-phase
        float T0 = 0.f, T1 = 0.f, T2 = 0.f, T3 = 0.f;
        if (lane == 3) T3 = 1.f;           // (h=0, w=15)
        float rs = (lane == 0) ? 1.f : 0.f; // rs-phase state, h = lane (0..15)
        const float4* actb = (const float4*)actions + (size_t)b * S_LEN;
        bf16* ob = wsT + ((size_t)b * NP + h4 * 16 + wq * 4) * S_LEN;

        // stage chunk 0 (act rows [1792, 2048))
#pragma unroll
        for (int j = 0; j < 4; ++j)
            gload16(actb + 1792 + j * 64 + lane, &sm.s.actbuf[0][j * 64]);

        for (int c = 0; c < 8; ++c) {
            const int chunkbase = 1792 - c * 256;
            asm volatile("s_waitcnt vmcnt(0)" ::: "memory");
            if (c < 7) {
#pragma unroll
                for (int j = 0; j < 4; ++j)
                    gload16(actb + (chunkbase - 256) + j * 64 + lane,
                            &sm.s.actbuf[(c + 1) & 1][j * 64]);
            }
            const float4* lb = sm.s.actbuf[c & 1];

            // ---- rs phase: 256 steps (t descending within chunk) ----
            for (int w = 0; w < 32; ++w) {
                const int rtop = 255 - w * 8;
                const float4 e0 = lb[rtop],     e1 = lb[rtop - 1];
                const float4 e2 = lb[rtop - 2], e3 = lb[rtop - 3];
                const float4 e4 = lb[rtop - 4], e5 = lb[rtop - 5];
                const float4 e6 = lb[rtop - 6], e7 = lb[rtop - 7];
#define RS_STEP(E, ro) do {                                                   \
        const float rsp = dpp_shr1_z(rs);                                     \
        const float sums = (E).y * rsp;                                       \
        if (lane < 16) sm.s.sums[rtop - (ro)][lane] = sums;                   \
        rs = fmaf((E).x + (E).z, rs, sums);                                   \
    } while (0)
                RS_STEP(e0, 0); RS_STEP(e1, 1); RS_STEP(e2, 2); RS_STEP(e3, 3);
                RS_STEP(e4, 4); RS_STEP(e5, 5); RS_STEP(e6, 6); RS_STEP(e7, 7);
#undef RS_STEP
            }

            // ---- T phase: 256 steps (t descending within chunk) ----
            for (int w = 0; w < 32; ++w) {
                const int rtop = 255 - w * 8;
                const int tglob = chunkbase + rtop - 7;
                const float4 av0 = lb[rtop],     av1 = lb[rtop - 1];
                const float4 av2 = lb[rtop - 2], av3 = lb[rtop - 3];
                const float4 av4 = lb[rtop - 4], av5 = lb[rtop - 5];
                const float4 av6 = lb[rtop - 6], av7 = lb[rtop - 7];
                const float su0 = sm.s.sums[rtop][h4],     su1 = sm.s.sums[rtop - 1][h4];
                const float su2 = sm.s.sums[rtop - 2][h4], su3 = sm.s.sums[rtop - 3][h4];
                const float su4 = sm.s.sums[rtop - 4][h4], su5 = sm.s.sums[rtop - 5][h4];
                const float su6 = sm.s.sums[rtop - 6][h4], su7 = sm.s.sums[rtop - 7][h4];
                bf16x8 fr0, fr1, fr2, fr3;
#define T_STEP(Av, Su, fi) do {                                               \
        const float a0 = (Av).x, a1 = (Av).y, a2 = (Av).z;                    \
        const float s01 = a0 + a1;                                            \
        fr0[fi] = (bf16)(s01 * T0);                                           \
        fr1[fi] = (bf16)(s01 * T1);                                           \
        fr2[fi] = (bf16)(s01 * T2);                                           \
        fr3[fi] = (bf16)(s01 * T3);                                           \
        const float nT0 = dpp_shl1_z(T0);                                     \
        const float qe = (wq == 3) ? (Su) : a0 * nT0;                         \
        const float q1 = a0 * T1, q2 = a0 * T2, q3 = a0 * T3;                 \
        T0 = fmaf(a2, T0, q1);                                                \
        T1 = fmaf(a2, T1, q2);                                                \
        T2 = fmaf(a2, T2, q3);                                                \
        T3 = fmaf(a2, T3, qe);                                                \
    } while (0)
                T_STEP(av0, su0, 7); T_STEP(av1, su1, 6);
                T_STEP(av2, su2, 5); T_STEP(av3, su3, 4);
                T_STEP(av4, su4, 3); T_STEP(av5, su5, 2);
                T_STEP(av6, su6, 1); T_STEP(av7, su7, 0);
#undef T_STEP
                *(bf16x8*)(ob + (size_t)0 * S_LEN + tglob) = fr0;
                *(bf16x8*)(ob + (size_t)1 * S_LEN + tglob) = fr1;
                *(bf16x8*)(ob + (size_t)2 * S_LEN + tglob) = fr2;
                *(bf16x8*)(ob + (size_t)3 * S_LEN + tglob) = fr3;
            }
        }
        return;
    }
    // ---- prep transpose path ----
    const int bid = blockIdx.x - 32;
    const int b = bid >> 8;
    const int r = bid & 255;
    const int s0 = (r & 31) << 6;
    const int e0 = (r >> 5) << 6;
    const int t = threadIdx.x;
    const int tx = t & 15, ty = t >> 4;
    const float* src = seq + ((size_t)b * S_LEN + s0) * NE + e0;
#pragma unroll
    for (int i = 0; i < 4; ++i) {
        const int row = ty + i * 16;
        const float4 v = *(const float4*)(src + (size_t)row * NE + tx * 4);
        sm.tile[row][tx * 4 + 0] = v.x; sm.tile[row][tx * 4 + 1] = v.y;
        sm.tile[row][tx * 4 + 2] = v.z; sm.tile[row][tx * 4 + 3] = v.w;
    }
    __syncthreads();
    const int sx = t & 7, ey = t >> 3;
#pragma unroll
    for (int jj = 0; jj < 2; ++jj) {
        const int er = ey + jj * 32;
        bf16x8 oh;
#pragma unroll
        for (int q = 0; q < 8; ++q) oh[q] = (bf16)sm.tile[sx * 8 + q][er];
        *(bf16x8*)(tHi + ((size_t)b * NE + e0 + er) * S_LEN + s0 + sx * 8) = oh;
    }
}

// ---------------- kernel 3: GEMM2 partials (2-way k-split, LDS-staged) ------
__global__ __launch_bounds__(256, 2) void k_gemm2(
    const bf16* __restrict__ wsT, const bf16* __restrict__ seqtH,
    float* __restrict__ part)
{
    __shared__ __align__(16) bf16 AL[2][4096];
    __shared__ __align__(16) bf16 BL[2][4096];
    const int tid = threadIdx.x;
    const int wid = tid >> 6;
    const int lane = tid & 63;
    const int lr = lane & 15, lg = lane >> 4;
    const int bid = blockIdx.x;
    const int b = bid >> 4;
    const int sub = bid & 15;
    const int kc = sub >> 3;
    const int p0 = ((sub >> 2) & 1) << 7;
    const int e0 = (sub & 3) << 7;

    const bf16* Abase = wsT + ((size_t)b * NP + p0) * S_LEN + kc * 1024;
    const bf16* Bbase = seqtH + ((size_t)b * NE + e0) * S_LEN + kc * 1024;
    const int lroff = lr * 64 + (lg ^ ((lr >> 1) & 3)) * 16;

    f32x4 acc[2][8];
#pragma unroll
    for (int i = 0; i < 2; ++i)
#pragma unroll
        for (int j = 0; j < 8; ++j) acc[i][j] = (f32x4)(0.f);

    stage_tile(Abase, S_LEN, AL[0], tid);
    stage_tile(Bbase, S_LEN, BL[0], tid);

#define G2_BODY(kt, buf) do {                                                 \
        __syncthreads();                                                      \
        bf16x8 af[2], bfv[8];                                                 \
        _Pragma("unroll") for (int i = 0; i < 2; ++i)                         \
            af[i] = *(const bf16x8*)((const char*)AL[buf]                     \
                     + (wid * 32 + i * 16) * 64 + lroff);                     \
        _Pragma("unroll") for (int j = 0; j < 8; ++j)                         \
            bfv[j] = *(const bf16x8*)((const char*)BL[buf] + j * 1024 + lroff);\
        __syncthreads();                                                      \
        if ((kt) < 31) {                                                      \
            stage_tile(Abase + ((kt) + 1) * 32, S_LEN, AL[(buf) ^ 1], tid);   \
            stage_tile(Bbase + ((kt) + 1) * 32, S_LEN, BL[(buf) ^ 1], tid);   \
        }                                                                     \
        _Pragma("unroll") for (int j = 0; j < 8; ++j) {                       \
            acc[0][j] = __builtin_amdgcn_mfma_f32_16x16x32_bf16(af[0], bfv[j], acc[0][j], 0, 0, 0); \
            acc[1][j] = __builtin_amdgcn_mfma_f32_16x16x32_bf16(af[1], bfv[j], acc[1][j], 0, 0, 0); \
        }                                                                     \
    } while (0)

    for (int kk = 0; kk < 16; ++kk) {
        G2_BODY(2 * kk, 0);
        G2_BODY(2 * kk + 1, 1);
    }
#undef G2_BODY

    float* obp = part + (((size_t)kc * NB + b) * NP + p0 + wid * 32) * NE + e0;
#pragma unroll
    for (int i = 0; i < 2; ++i)
#pragma unroll
        for (int j = 0; j < 8; ++j)
#pragma unroll
            for (int q = 0; q < 4; ++q)
                obp[(size_t)(i * 16 + lg * 4 + q) * NE + j * 16 + lr] = acc[i][j][q];
}

// ---------------- kernel 4: reduce the 2 partials ---------------------------
__global__ __launch_bounds__(256) void k_gred(
    const float* __restrict__ part, float* __restrict__ outp)
{
    const size_t i = ((size_t)blockIdx.x * 256 + threadIdx.x) * 4;
    const float4 p0 = *(const float4*)(part + i);
    const float4 p1 = *(const float4*)(part + ((size_t)NB * NP * NE) + i);
    *(float4*)(outp + i) = make_float4(p0.x + p1.x, p0.y + p1.y,
                                       p0.z + p1.z, p0.w + p1.w);
}

// ---------------- launch ----------------------------------------------------
extern "C" void kernel_launch(void* const* d_in, const int* in_sizes, int n_in,
                              void* d_out, int out_size, void* d_ws, size_t ws_size,
                              hipStream_t stream) {
    (void)in_sizes; (void)n_in; (void)out_size; (void)ws_size;
    const float* seq = (const float*)d_in[0];
    const float* w1  = (const float*)d_in[1];
    const float* b1  = (const float*)d_in[2];
    const float* w2  = (const float*)d_in[3];
    const float* b2  = (const float*)d_in[4];
    float* outp = (float*)d_out;

    char* ws = (char*)d_ws;
    bf16*  seqtH   = (bf16*)(ws);                        // 64 MB [b][e][s]
    bf16*  wsT     = (bf16*)(ws + (64ull << 20));        // 32 MB [b][p][t]
    float* actions = (float*)(ws + (96ull << 20));       // 1 MB  [b*S][4]
    bf16*  w1H     = (bf16*)(ws + (97ull << 20));        // 512 KB
    bf16*  w1L     = (bf16*)(ws + (97ull << 20) + (512u << 10)); // 512 KB
    float* part    = (float*)(ws + (98ull << 20));       // 32 MB [2][b][p][e]

    hipLaunchKernelGGL(k_wconv, dim3(256),  dim3(256), 0, stream, w1, w1H, w1L);
    hipLaunchKernelGGL(k_gemm1, dim3(512),  dim3(256), 0, stream,
                       seq, w1H, w1L, b1, w2, b2, actions);
    hipLaunchKernelGGL(k_scan_prep, dim3(32 + 8192), dim3(256), 0, stream,
                       actions, wsT, seq, seqtH);
    hipLaunchKernelGGL(k_gemm2, dim3(512),  dim3(256), 0, stream, wsT, seqtH, part);
    hipLaunchKernelGGL(k_gred,  dim3(4096), dim3(256), 0, stream, part, outp);
}

// Round 6
// 289.399 us; speedup vs baseline: 1.4118x; 1.3156x over previous
//
#include <hip/hip_runtime.h>
#include <stdint.h>

#define S_LEN 2048
#define NB 32
#define NE 512
#define NU 512
#define NP 256

typedef __bf16 bf16;
typedef __bf16 bf16x8 __attribute__((ext_vector_type(8)));
typedef __bf16 bf16x4 __attribute__((ext_vector_type(4)));
typedef float f32x4 __attribute__((ext_vector_type(4)));
typedef float f32x8 __attribute__((ext_vector_type(8)));

__device__ __forceinline__ void gload16(const void* g, void* l) {
    __builtin_amdgcn_global_load_lds(
        (__attribute__((address_space(1))) void*)g,
        (__attribute__((address_space(3))) void*)l, 16, 0, 0);
}

// DPP helpers: VALU-pipe lane shifts within 16-lane rows, bound_ctrl -> 0.
// HW-verified (rounds 4/5 passed with identical usage):
//   0x111 row_shr:1 -> lane i reads lane i-1 ; 0x101 row_shl:1 -> lane i reads lane i+1
__device__ __forceinline__ float dpp_shr1_z(float x) {
    return __builtin_bit_cast(float, __builtin_amdgcn_update_dpp(
        0, __builtin_bit_cast(int, x), 0x111, 0xF, 0xF, true));
}
__device__ __forceinline__ float dpp_shl1_z(float x) {
    return __builtin_bit_cast(float, __builtin_amdgcn_update_dpp(
        0, __builtin_bit_cast(int, x), 0x101, 0xF, 0xF, true));
}

// Stage a 128-row x 32-col bf16 tile (row stride SR elems) into an 8KB LDS
// buffer, 2 chunks per thread; self-inverse k-quad permutation.
__device__ __forceinline__ void stage_tile(const bf16* __restrict__ src, int SR,
                                           bf16* lds, int tid) {
#pragma unroll
    for (int rnd = 0; rnd < 2; ++rnd) {
        const int c = rnd * 256 + tid;
        const int row = c >> 2;
        const int q = (c & 3) ^ ((c >> 3) & 3);
        gload16(src + (size_t)row * SR + q * 8, lds + c * 8);
    }
}

// ---------------- kernel 0b: w1 fp32 -> bf16 hi/lo --------------------------
__global__ __launch_bounds__(256) void k_wconv(
    const float* __restrict__ w1, bf16* __restrict__ wHi, bf16* __restrict__ wLo)
{
    const int i = (blockIdx.x * 256 + threadIdx.x) * 4;
    const float4 v = *(const float4*)(w1 + i);
    const float vv[4] = {v.x, v.y, v.z, v.w};
    bf16x4 oh, ol;
#pragma unroll
    for (int q = 0; q < 4; ++q) {
        const bf16 hb = (bf16)vv[q];
        oh[q] = hb;
        ol[q] = (bf16)(vv[q] - (float)hb);
    }
    *(bf16x4*)(wHi + i) = oh;
    *(bf16x4*)(wLo + i) = ol;
}

// ---------------- kernel 1: GEMM1 + silu + logits + softmax -----------------
__global__ __launch_bounds__(256, 2) void k_gemm1(
    const float* __restrict__ seq,
    const bf16* __restrict__ w1H, const bf16* __restrict__ w1L,
    const float* __restrict__ b1v, const float* __restrict__ w2,
    const float* __restrict__ b2v, float* __restrict__ actions)
{
    __shared__ __align__(16) bf16 BhL[2][4096];
    __shared__ __align__(16) bf16 BlL[2][4096];
    const int tid = threadIdx.x;
    const int wid = tid >> 6;
    const int lane = tid & 63;
    const int lr = lane & 15, lg = lane >> 4;
    const int m0 = blockIdx.x << 7;

    const float* arow0 = seq + (size_t)(m0 + wid * 32 + lr) * NE + lg * 8;
    const float* arow1 = arow0 + 16 * NE;
    const int lroff = lr * 64 + (lg ^ ((lr >> 1) & 3)) * 16;

    float plog[3][2][4];
#pragma unroll
    for (int a = 0; a < 3; ++a)
#pragma unroll
        for (int i = 0; i < 2; ++i)
#pragma unroll
            for (int q = 0; q < 4; ++q) plog[a][i][q] = 0.f;

    f32x4 acc[2][8];
    stage_tile(w1H, NE, BhL[0], tid);
    stage_tile(w1L, NE, BlL[0], tid);
    f32x8 Aa0 = *(const f32x8*)(arow0);
    f32x8 Aa1 = *(const f32x8*)(arow1);
    f32x8 Ab0, Ab1;

#define G1_BODY(g, buf, Ac0, Ac1, An0, An1) do {                              \
        __syncthreads();                                                      \
        if (((g) & 15) == 0) {                                                \
            _Pragma("unroll") for (int i = 0; i < 2; ++i)                     \
            _Pragma("unroll") for (int j = 0; j < 8; ++j)                     \
                acc[i][j] = (f32x4)(0.f);                                     \
        }                                                                     \
        bf16x8 bh[8], bl[8];                                                  \
        _Pragma("unroll") for (int j = 0; j < 8; ++j) {                       \
            bh[j] = *(const bf16x8*)((const char*)BhL[buf] + j * 1024 + lroff);\
            bl[j] = *(const bf16x8*)((const char*)BlL[buf] + j * 1024 + lroff);\
        }                                                                     \
        __syncthreads();                                                      \
        if ((g) < 63) {                                                       \
            const int gn = (g) + 1;                                           \
            const int u0n = (gn >> 4) << 7;                                   \
            const int k0n = (gn & 15) << 5;                                   \
            stage_tile(w1H + (size_t)u0n * NE + k0n, NE, BhL[(buf) ^ 1], tid);\
            stage_tile(w1L + (size_t)u0n * NE + k0n, NE, BlL[(buf) ^ 1], tid);\
            An0 = *(const f32x8*)(arow0 + k0n);                               \
            An1 = *(const f32x8*)(arow1 + k0n);                               \
        }                                                                     \
        bf16x8 Ah0, Al0, Ah1, Al1;                                            \
        _Pragma("unroll") for (int q = 0; q < 8; ++q) {                       \
            const bf16 h0 = (bf16)Ac0[q];                                     \
            Ah0[q] = h0; Al0[q] = (bf16)(Ac0[q] - (float)h0);                 \
            const bf16 h1 = (bf16)Ac1[q];                                     \
            Ah1[q] = h1; Al1[q] = (bf16)(Ac1[q] - (float)h1);                 \
        }                                                                     \
        _Pragma("unroll") for (int j = 0; j < 8; ++j) {                       \
            acc[0][j] = __builtin_amdgcn_mfma_f32_16x16x32_bf16(Ah0, bh[j], acc[0][j], 0, 0, 0); \
            acc[0][j] = __builtin_amdgcn_mfma_f32_16x16x32_bf16(Ah0, bl[j], acc[0][j], 0, 0, 0); \
            acc[0][j] = __builtin_amdgcn_mfma_f32_16x16x32_bf16(Al0, bh[j], acc[0][j], 0, 0, 0); \
            acc[1][j] = __builtin_amdgcn_mfma_f32_16x16x32_bf16(Ah1, bh[j], acc[1][j], 0, 0, 0); \
            acc[1][j] = __builtin_amdgcn_mfma_f32_16x16x32_bf16(Ah1, bl[j], acc[1][j], 0, 0, 0); \
            acc[1][j] = __builtin_amdgcn_mfma_f32_16x16x32_bf16(Al1, bh[j], acc[1][j], 0, 0, 0); \
        }                                                                     \
        if (((g) & 15) == 15) {                                               \
            const int u0 = ((g) >> 4) << 7;                                   \
            _Pragma("unroll") for (int j = 0; j < 8; ++j) {                   \
                const int col = u0 + j * 16 + lr;                             \
                const float b1c = b1v[col];                                   \
                const float w20 = w2[col], w21 = w2[NU + col], w22 = w2[2 * NU + col]; \
                _Pragma("unroll") for (int i = 0; i < 2; ++i)                 \
                _Pragma("unroll") for (int q = 0; q < 4; ++q) {               \
                    const float x = acc[i][j][q] + b1c;                       \
                    const float hgate = x / (1.f + __expf(-x));               \
                    plog[0][i][q] = fmaf(hgate, w20, plog[0][i][q]);          \
                    plog[1][i][q] = fmaf(hgate, w21, plog[1][i][q]);          \
                    plog[2][i][q] = fmaf(hgate, w22, plog[2][i][q]);          \
                }                                                             \
            }                                                                 \
        }                                                                     \
    } while (0)

    for (int gg = 0; gg < 32; ++gg) {
        G1_BODY(2 * gg, 0, Aa0, Aa1, Ab0, Ab1);
        G1_BODY(2 * gg + 1, 1, Ab0, Ab1, Aa0, Aa1);
    }
#undef G1_BODY

#pragma unroll
    for (int m = 1; m < 16; m <<= 1) {
#pragma unroll
        for (int a = 0; a < 3; ++a)
#pragma unroll
            for (int i = 0; i < 2; ++i)
#pragma unroll
                for (int q = 0; q < 4; ++q)
                    plog[a][i][q] += __shfl_xor(plog[a][i][q], m);
    }
    const float bb0 = b2v[0], bb1 = b2v[1], bb2 = b2v[2];
    if (lr == 0) {
#pragma unroll
        for (int i = 0; i < 2; ++i)
#pragma unroll
            for (int q = 0; q < 4; ++q) {
                const int row = m0 + wid * 32 + i * 16 + lg * 4 + q;
                const float l0 = plog[0][i][q] + bb0;
                const float l1 = plog[1][i][q] + bb1;
                const float l2 = plog[2][i][q] + bb2;
                const float mx = fmaxf(l0, fmaxf(l1, l2));
                const float e0 = __expf(l0 - mx), e1 = __expf(l1 - mx), e2 = __expf(l2 - mx);
                const float inv = 1.f / (e0 + e1 + e2);
                *(float4*)(actions + (size_t)row * 4) = make_float4(e0 * inv, e1 * inv, e2 * inv, 0.f);
            }
    }
}

// ---------------- fused kernel: scan (blocks 0..31) + prep transpose --------
// 5 waves per scan block: wave 4 = rs producer (one chunk ahead, DPP shr1),
// waves 0..3 = T consumers, ONE cell per lane (lane = h_local*16 + w,
// p = wid*64 + lane). T[w+1] = lane+1 via DPP shl1; w==15 takes sums from LDS.
// act rotates through 3 LDS buffers (global_load_lds issued by consumers one
// iteration ahead, vmcnt(0) drained before the publishing barrier).
union SPMem {
    float tile[64][65];                    // prep path (16.6 KB)
    struct {
        float4 actbuf[3][256];             // 12 KB
        float  sums[2][256][16];           // 32 KB
    } s;
};

__device__ __forceinline__ void rs_chunk(const float4* __restrict__ pb,
                                         float* __restrict__ so,
                                         float& rs, int lane)
{
    for (int w = 0; w < 32; ++w) {
        const int rtop = 255 - w * 8;
        const float4 e0 = pb[rtop],     e1 = pb[rtop - 1];
        const float4 e2 = pb[rtop - 2], e3 = pb[rtop - 3];
        const float4 e4 = pb[rtop - 4], e5 = pb[rtop - 5];
        const float4 e6 = pb[rtop - 6], e7 = pb[rtop - 7];
#define RS_STEP(E, k) do {                                                    \
        const float rsp = dpp_shr1_z(rs);                                     \
        const float s = (E).y * rsp;                                          \
        if (lane < 16) so[(rtop - (k)) * 16 + lane] = s;                      \
        rs = fmaf((E).x + (E).z, rs, s);                                      \
    } while (0)
        RS_STEP(e0, 0); RS_STEP(e1, 1); RS_STEP(e2, 2); RS_STEP(e3, 3);
        RS_STEP(e4, 4); RS_STEP(e5, 5); RS_STEP(e6, 6); RS_STEP(e7, 7);
#undef RS_STEP
    }
}

__device__ __forceinline__ void t_chunk(const float4* __restrict__ lb,
                                        const float* __restrict__ sp,
                                        float& T, bf16* __restrict__ obp,
                                        int tbase0, int w15)
{
    for (int w = 0; w < 32; ++w) {
        const int rtop = 255 - w * 8;
        const int tglob = tbase0 + rtop - 7;
        const float4 av0 = lb[rtop],     av1 = lb[rtop - 1];
        const float4 av2 = lb[rtop - 2], av3 = lb[rtop - 3];
        const float4 av4 = lb[rtop - 4], av5 = lb[rtop - 5];
        const float4 av6 = lb[rtop - 6], av7 = lb[rtop - 7];
        const float su0 = sp[rtop * 16],       su1 = sp[(rtop - 1) * 16];
        const float su2 = sp[(rtop - 2) * 16], su3 = sp[(rtop - 3) * 16];
        const float su4 = sp[(rtop - 4) * 16], su5 = sp[(rtop - 5) * 16];
        const float su6 = sp[(rtop - 6) * 16], su7 = sp[(rtop - 7) * 16];
        bf16x8 fr;
#define T_STEP(Av, Su, fi) do {                                               \
        const float a0 = (Av).x, a1 = (Av).y, a2 = (Av).z;                    \
        fr[fi] = (bf16)((a0 + a1) * T);                                       \
        const float nT = dpp_shl1_z(T);                                       \
        const float contrib = w15 ? (Su) : a0 * nT;                           \
        T = fmaf(a2, T, contrib);                                             \
    } while (0)
        T_STEP(av0, su0, 7); T_STEP(av1, su1, 6);
        T_STEP(av2, su2, 5); T_STEP(av3, su3, 4);
        T_STEP(av4, su4, 3); T_STEP(av5, su5, 2);
        T_STEP(av6, su6, 1); T_STEP(av7, su7, 0);
#undef T_STEP
        *(bf16x8*)(obp + tglob) = fr;
    }
}

__global__ __launch_bounds__(320) void k_scan_prep(
    const float* __restrict__ actions, bf16* __restrict__ wsT,
    const float* __restrict__ seq, bf16* __restrict__ tHi)
{
    __shared__ SPMem sm;
    const int tid = threadIdx.x;
    if (blockIdx.x < 32) {
        const int b = blockIdx.x;
        const int wid = tid >> 6;
        const int lane = tid & 63;
        const float4* actb = (const float4*)actions + (size_t)b * S_LEN;

        float rs = (lane == 0) ? 1.f : 0.f;                 // producer state (h = lane&15)
        float T = (wid == 0 && lane == 15) ? 1.f : 0.f;     // consumer cell (h=0,w=15)=1
        const int w15 = ((lane & 15) == 15) ? 1 : 0;
        bf16* obp = wsT + ((size_t)b * NP + wid * 64 + lane) * S_LEN;

        // prologue: load chunks 0,1; rs chunk 0 -> sums[0]
        if (wid < 4) {
            gload16(actb + 1792 + wid * 64 + lane, &sm.s.actbuf[0][wid * 64]);
            gload16(actb + 1536 + wid * 64 + lane, &sm.s.actbuf[1][wid * 64]);
            asm volatile("s_waitcnt vmcnt(0)" ::: "memory");
        }
        __syncthreads();
        if (wid == 4) rs_chunk(sm.s.actbuf[0], &sm.s.sums[0][0][0], rs, lane);
        __syncthreads();

        int bufT = 0, bufP = 1, bufL = 2;
        for (int c = 0; c < 8; ++c) {
            if (wid < 4) {
                if (c < 6)
                    gload16(actb + (1280 - c * 256) + wid * 64 + lane,
                            &sm.s.actbuf[bufL][wid * 64]);
                t_chunk(sm.s.actbuf[bufT],
                        &sm.s.sums[c & 1][0][wid * 4 + (lane >> 4)],
                        T, obp, 1792 - c * 256, w15);
                asm volatile("s_waitcnt vmcnt(0)" ::: "memory");
            } else {
                if (c < 7)
                    rs_chunk(sm.s.actbuf[bufP], &sm.s.sums[(c + 1) & 1][0][0], rs, lane);
            }
            __syncthreads();
            const int t = bufT; bufT = bufP; bufP = bufL; bufL = t;
        }
        return;
    }
    // ---- prep transpose path (all 320 threads hit the barrier) ----
    const int bid = blockIdx.x - 32;
    const int b = bid >> 8;
    const int r = bid & 255;
    const int s0 = (r & 31) << 6;
    const int e0 = (r >> 5) << 6;
    const int tx = tid & 15, ty = (tid & 255) >> 4;
    const float* src = seq + ((size_t)b * S_LEN + s0) * NE + e0;
    if (tid < 256) {
#pragma unroll
        for (int i = 0; i < 4; ++i) {
            const int row = ty + i * 16;
            const float4 v = *(const float4*)(src + (size_t)row * NE + tx * 4);
            sm.tile[row][tx * 4 + 0] = v.x; sm.tile[row][tx * 4 + 1] = v.y;
            sm.tile[row][tx * 4 + 2] = v.z; sm.tile[row][tx * 4 + 3] = v.w;
        }
    }
    __syncthreads();
    if (tid < 256) {
        const int sx = tid & 7, ey = tid >> 3;
#pragma unroll
        for (int jj = 0; jj < 2; ++jj) {
            const int er = ey + jj * 32;
            bf16x8 oh;
#pragma unroll
            for (int q = 0; q < 8; ++q) oh[q] = (bf16)sm.tile[sx * 8 + q][er];
            *(bf16x8*)(tHi + ((size_t)b * NE + e0 + er) * S_LEN + s0 + sx * 8) = oh;
        }
    }
}

// ---------------- kernel 3: GEMM2 partials (2-way k-split, LDS-staged) ------
__global__ __launch_bounds__(256, 2) void k_gemm2(
    const bf16* __restrict__ wsT, const bf16* __restrict__ seqtH,
    float* __restrict__ part)
{
    __shared__ __align__(16) bf16 AL[2][4096];
    __shared__ __align__(16) bf16 BL[2][4096];
    const int tid = threadIdx.x;
    const int wid = tid >> 6;
    const int lane = tid & 63;
    const int lr = lane & 15, lg = lane >> 4;
    const int bid = blockIdx.x;
    const int b = bid >> 4;
    const int sub = bid & 15;
    const int kc = sub >> 3;
    const int p0 = ((sub >> 2) & 1) << 7;
    const int e0 = (sub & 3) << 7;

    const bf16* Abase = wsT + ((size_t)b * NP + p0) * S_LEN + kc * 1024;
    const bf16* Bbase = seqtH + ((size_t)b * NE + e0) * S_LEN + kc * 1024;
    const int lroff = lr * 64 + (lg ^ ((lr >> 1) & 3)) * 16;

    f32x4 acc[2][8];
#pragma unroll
    for (int i = 0; i < 2; ++i)
#pragma unroll
        for (int j = 0; j < 8; ++j) acc[i][j] = (f32x4)(0.f);

    stage_tile(Abase, S_LEN, AL[0], tid);
    stage_tile(Bbase, S_LEN, BL[0], tid);

#define G2_BODY(kt, buf) do {                                                 \
        __syncthreads();                                                      \
        bf16x8 af[2], bfv[8];                                                 \
        _Pragma("unroll") for (int i = 0; i < 2; ++i)                         \
            af[i] = *(const bf16x8*)((const char*)AL[buf]                     \
                     + (wid * 32 + i * 16) * 64 + lroff);                     \
        _Pragma("unroll") for (int j = 0; j < 8; ++j)                         \
            bfv[j] = *(const bf16x8*)((const char*)BL[buf] + j * 1024 + lroff);\
        __syncthreads();                                                      \
        if ((kt) < 31) {                                                      \
            stage_tile(Abase + ((kt) + 1) * 32, S_LEN, AL[(buf) ^ 1], tid);   \
            stage_tile(Bbase + ((kt) + 1) * 32, S_LEN, BL[(buf) ^ 1], tid);   \
        }                                                                     \
        _Pragma("unroll") for (int j = 0; j < 8; ++j) {                       \
            acc[0][j] = __builtin_amdgcn_mfma_f32_16x16x32_bf16(af[0], bfv[j], acc[0][j], 0, 0, 0); \
            acc[1][j] = __builtin_amdgcn_mfma_f32_16x16x32_bf16(af[1], bfv[j], acc[1][j], 0, 0, 0); \
        }                                                                     \
    } while (0)

    for (int kk = 0; kk < 16; ++kk) {
        G2_BODY(2 * kk, 0);
        G2_BODY(2 * kk + 1, 1);
    }
#undef G2_BODY

    float* obp = part + (((size_t)kc * NB + b) * NP + p0 + wid * 32) * NE + e0;
#pragma unroll
    for (int i = 0; i < 2; ++i)
#pragma unroll
        for (int j = 0; j < 8; ++j)
#pragma unroll
            for (int q = 0; q < 4; ++q)
                obp[(size_t)(i * 16 + lg * 4 + q) * NE + j * 16 + lr] = acc[i][j][q];
}

// ---------------- kernel 4: reduce the 2 partials ---------------------------
__global__ __launch_bounds__(256) void k_gred(
    const float* __restrict__ part, float* __restrict__ outp)
{
    const size_t i = ((size_t)blockIdx.x * 256 + threadIdx.x) * 4;
    const float4 p0 = *(const float4*)(part + i);
    const float4 p1 = *(const float4*)(part + ((size_t)NB * NP * NE) + i);
    *(float4*)(outp + i) = make_float4(p0.x + p1.x, p0.y + p1.y,
                                       p0.z + p1.z, p0.w + p1.w);
}

// ---------------- launch ----------------------------------------------------
extern "C" void kernel_launch(void* const* d_in, const int* in_sizes, int n_in,
                              void* d_out, int out_size, void* d_ws, size_t ws_size,
                              hipStream_t stream) {
    (void)in_sizes; (void)n_in; (void)out_size; (void)ws_size;
    const float* seq = (const float*)d_in[0];
    const float* w1  = (const float*)d_in[1];
    const float* b1  = (const float*)d_in[2];
    const float* w2  = (const float*)d_in[3];
    const float* b2  = (const float*)d_in[4];
    float* outp = (float*)d_out;

    char* ws = (char*)d_ws;
    bf16*  seqtH   = (bf16*)(ws);                        // 64 MB [b][e][s]
    bf16*  wsT     = (bf16*)(ws + (64ull << 20));        // 32 MB [b][p][t]
    float* actions = (float*)(ws + (96ull << 20));       // 1 MB  [b*S][4]
    bf16*  w1H     = (bf16*)(ws + (97ull << 20));        // 512 KB
    bf16*  w1L     = (bf16*)(ws + (97ull << 20) + (512u << 10)); // 512 KB
    float* part    = (float*)(ws + (98ull << 20));       // 32 MB [2][b][p][e]

    hipLaunchKernelGGL(k_wconv, dim3(256),  dim3(256), 0, stream, w1, w1H, w1L);
    hipLaunchKernelGGL(k_gemm1, dim3(512),  dim3(256), 0, stream,
                       seq, w1H, w1L, b1, w2, b2, actions);
    hipLaunchKernelGGL(k_scan_prep, dim3(32 + 8192), dim3(320), 0, stream,
                       actions, wsT, seq, seqtH);
    hipLaunchKernelGGL(k_gemm2, dim3(512),  dim3(256), 0, stream, wsT, seqtH, part);
    hipLaunchKernelGGL(k_gred,  dim3(4096), dim3(256), 0, stream, part, outp);
}